// Round 1
// baseline (362.335 us; speedup 1.0000x reference)
//
#include <hip/hip_runtime.h>

#define M_DIM 4096
#define N_DIM 4096
#define K_DIM 4096

typedef float f32x4 __attribute__((ext_vector_type(4)));
typedef __bf16 bf16x8 __attribute__((ext_vector_type(8)));

// round-to-nearest-even fp32 -> bf16
__device__ __forceinline__ unsigned short f2b(float f) {
    unsigned int u = __float_as_uint(f);
    u += 0x7fffu + ((u >> 16) & 1u);
    return (unsigned short)(u >> 16);
}

__device__ __constant__ float NVFP4_CODE[16] = {
    0.0f, 0.5f, 1.0f, 1.5f, 2.0f, 3.0f, 4.0f, 6.0f,
    -0.0f, -0.5f, -1.0f, -1.5f, -2.0f, -3.0f, -4.0f, -6.0f
};

// ---------------------------------------------------------------------------
// Kernel 1: x fp32 -> bf16   (16.7M elems, 8/thread)
// ---------------------------------------------------------------------------
__global__ __launch_bounds__(256) void cvt_x_kernel(const float* __restrict__ x,
                                                    unsigned short* __restrict__ xb) {
    size_t i = ((size_t)blockIdx.x * 256 + threadIdx.x) * 8;
    float4 a = *(const float4*)(x + i);
    float4 b = *(const float4*)(x + i + 4);
    union { unsigned short h[8]; uint4 u; } o;
    o.h[0] = f2b(a.x); o.h[1] = f2b(a.y); o.h[2] = f2b(a.z); o.h[3] = f2b(a.w);
    o.h[4] = f2b(b.x); o.h[5] = f2b(b.y); o.h[6] = f2b(b.z); o.h[7] = f2b(b.w);
    *(uint4*)(xb + i) = o.u;
}

// ---------------------------------------------------------------------------
// Kernel 2: build permuted+dequantized W_bf16 [N,K].
// One block per output channel j; g = inv_perm[j] picks the grouped row.
//   g <  2048        : NVFP4  w = code[idx]*scale[k/16]*gscale
//   2048 <= g < 3072 : FP8    w = w_fp8 * fp8_scale
//   else             : FP16   w = w_fp16
// Thread t handles k in [16t, 16t+16) == exactly one NVFP4 scale block.
// ---------------------------------------------------------------------------
__global__ __launch_bounds__(256) void build_w_kernel(
        const int* __restrict__ idx4, const float* __restrict__ sc4,
        const float* __restrict__ gs4, const float* __restrict__ w8,
        const float* __restrict__ s8, const float* __restrict__ w16,
        const int* __restrict__ iperm, unsigned short* __restrict__ W) {
    const int j = blockIdx.x;
    const int t = threadIdx.x;
    const int g = iperm[j];
    const int k0 = t * 16;
    union { unsigned short h[16]; uint4 u[2]; } o;

    if (g < 2048) {
        const float s = sc4[(size_t)g * (K_DIM / 16) + t] * gs4[0];
        const int4* ip = (const int4*)(idx4 + (size_t)g * K_DIM + k0);
#pragma unroll
        for (int b = 0; b < 4; ++b) {
            int4 v = ip[b];
            o.h[b * 4 + 0] = f2b(NVFP4_CODE[v.x & 15] * s);
            o.h[b * 4 + 1] = f2b(NVFP4_CODE[v.y & 15] * s);
            o.h[b * 4 + 2] = f2b(NVFP4_CODE[v.z & 15] * s);
            o.h[b * 4 + 3] = f2b(NVFP4_CODE[v.w & 15] * s);
        }
    } else if (g < 3072) {
        const float s = s8[0];
        const float4* wp = (const float4*)(w8 + (size_t)(g - 2048) * K_DIM + k0);
#pragma unroll
        for (int b = 0; b < 4; ++b) {
            float4 v = wp[b];
            o.h[b * 4 + 0] = f2b(v.x * s); o.h[b * 4 + 1] = f2b(v.y * s);
            o.h[b * 4 + 2] = f2b(v.z * s); o.h[b * 4 + 3] = f2b(v.w * s);
        }
    } else {
        const float4* wp = (const float4*)(w16 + (size_t)(g - 3072) * K_DIM + k0);
#pragma unroll
        for (int b = 0; b < 4; ++b) {
            float4 v = wp[b];
            o.h[b * 4 + 0] = f2b(v.x); o.h[b * 4 + 1] = f2b(v.y);
            o.h[b * 4 + 2] = f2b(v.z); o.h[b * 4 + 3] = f2b(v.w);
        }
    }
    uint4* dst = (uint4*)(W + (size_t)j * K_DIM + k0);
    dst[0] = o.u[0];
    dst[1] = o.u[1];
}

// ---------------------------------------------------------------------------
// Kernel 3: C[M,N] = Xb[M,K] * Wb[N,K]^T + bias   (m97-structure bf16 GEMM)
// 128x128 tile, BK=32, 4 waves 2x2, 4x4 frags of mfma_f32_16x16x32_bf16,
// global_load_lds width-16 staging (lane-contiguous LDS layout).
// ---------------------------------------------------------------------------
#define GLOAD_LDS16(g, l)                                                     \
    __builtin_amdgcn_global_load_lds(                                         \
        (const __attribute__((address_space(1))) void*)(unsigned long long)(g),\
        (__attribute__((address_space(3))) void*)(unsigned int)(unsigned long long)(l), \
        16, 0, 0)

__global__ __launch_bounds__(256) void gemm_kernel(
        const unsigned short* __restrict__ X, const unsigned short* __restrict__ W,
        const float* __restrict__ bias, float* __restrict__ C) {
    __shared__ __align__(16) unsigned short As[128 * 32];
    __shared__ __align__(16) unsigned short Bs[128 * 32];

    const int tid  = threadIdx.x;
    const int wave = tid >> 6;
    const int lane = tid & 63;
    const int quad = lane >> 4;
    const int l16  = lane & 15;
    const int wr   = wave >> 1;   // wave row (0..1) -> 64 rows of C
    const int wc   = wave & 1;    // wave col (0..1) -> 64 cols of C
    const int m0 = blockIdx.y * 128;
    const int n0 = blockIdx.x * 128;

    // staging chunks: 512 16B-chunks per 128x32 tile, 2 per thread per tile
    const int c0 = wave * 64 + lane;   // 0..255
    const int c1 = c0 + 256;           // 256..511
    const int rA0 = c0 >> 2, kc0 = (c0 & 3) * 8;
    const int rA1 = c1 >> 2, kc1 = (c1 & 3) * 8;

    const unsigned short* Xa0 = X + (size_t)(m0 + rA0) * K_DIM + kc0;
    const unsigned short* Xa1 = X + (size_t)(m0 + rA1) * K_DIM + kc1;
    const unsigned short* Wb0 = W + (size_t)(n0 + rA0) * K_DIM + kc0;
    const unsigned short* Wb1 = W + (size_t)(n0 + rA1) * K_DIM + kc1;

    f32x4 acc[4][4] = {};

    for (int kt = 0; kt < K_DIM / 32; ++kt) {
        const int k0 = kt * 32;
        GLOAD_LDS16(Xa0 + k0, &As[c0 * 8]);
        GLOAD_LDS16(Xa1 + k0, &As[c1 * 8]);
        GLOAD_LDS16(Wb0 + k0, &Bs[c0 * 8]);
        GLOAD_LDS16(Wb1 + k0, &Bs[c1 * 8]);
        __syncthreads();   // drains vmcnt(0): DMA complete

        bf16x8 af[4], bq[4];
#pragma unroll
        for (int i = 0; i < 4; ++i)
            af[i] = *(const bf16x8*)&As[(wr * 64 + i * 16 + l16) * 32 + quad * 8];
#pragma unroll
        for (int jj = 0; jj < 4; ++jj)
            bq[jj] = *(const bf16x8*)&Bs[(wc * 64 + jj * 16 + l16) * 32 + quad * 8];

#pragma unroll
        for (int i = 0; i < 4; ++i)
#pragma unroll
            for (int jj = 0; jj < 4; ++jj)
                acc[i][jj] = __builtin_amdgcn_mfma_f32_16x16x32_bf16(
                    af[i], bq[jj], acc[i][jj], 0, 0, 0);

        __syncthreads();   // protect LDS before next stage
    }

    // epilogue: C/D layout col=lane&15, row=(lane>>4)*4+reg
#pragma unroll
    for (int jj = 0; jj < 4; ++jj) {
        const int col = n0 + wc * 64 + jj * 16 + l16;
        const float bv = bias[col];
#pragma unroll
        for (int i = 0; i < 4; ++i) {
            const int rowb = m0 + wr * 64 + i * 16 + quad * 4;
#pragma unroll
            for (int r = 0; r < 4; ++r)
                C[(size_t)(rowb + r) * N_DIM + col] = acc[i][jj][r] + bv;
        }
    }
}

// ---------------------------------------------------------------------------
extern "C" void kernel_launch(void* const* d_in, const int* in_sizes, int n_in,
                              void* d_out, int out_size, void* d_ws, size_t ws_size,
                              hipStream_t stream) {
    const float* x            = (const float*)d_in[0];
    const int*   nvfp4_idx    = (const int*)d_in[1];
    const float* nvfp4_scales = (const float*)d_in[2];
    const float* gscale       = (const float*)d_in[3];
    const float* w_fp8        = (const float*)d_in[4];
    const float* fp8_scale    = (const float*)d_in[5];
    const float* w_fp16       = (const float*)d_in[6];
    const float* bias         = (const float*)d_in[7];
    const int*   inv_perm     = (const int*)d_in[8];
    float* out = (float*)d_out;

    unsigned short* xb = (unsigned short*)d_ws;                 // 32 MiB
    unsigned short* wb = xb + (size_t)M_DIM * K_DIM;            // 32 MiB

    cvt_x_kernel<<<(M_DIM * (size_t)K_DIM) / (256 * 8), 256, 0, stream>>>(x, xb);
    build_w_kernel<<<N_DIM, 256, 0, stream>>>(nvfp4_idx, nvfp4_scales, gscale,
                                              w_fp8, fp8_scale, w_fp16, inv_perm, wb);
    gemm_kernel<<<dim3(N_DIM / 128, M_DIM / 128), 256, 0, stream>>>(xb, wb, bias, out);
}